// Round 2
// baseline (695.928 us; speedup 1.0000x reference)
//
#include <hip/hip_runtime.h>

namespace {

constexpr int H = 17, W = 17, NC = H * W;   // 289 cells
constexpr int SW = 20, SH = 19;             // LDS tile with 1-wide zero halo
constexpr int NT = 256;                     // 4 waves, one workgroup, 1 wave/SIMD
constexpr int TAIL = NC - NT;               // 33 tail cells handled by wave 0

__device__ __forceinline__ float clip10(float v) {
    return fminf(fmaxf(v, -10.f), 10.f);
}

__device__ __forceinline__ float scent_at(int hy, int wx, const float* __restrict__ food) {
    const float SK[5][5] = {
        {0.f,   .125f, .25f, .125f, 0.f},
        {.125f, .25f,  .5f,  .25f,  .125f},
        {.25f,  .5f,   1.f,  .5f,   .25f},
        {.125f, .25f,  .5f,  .25f,  .125f},
        {0.f,   .125f, .25f, .125f, 0.f}};
    float sc = 0.f;
    #pragma unroll
    for (int dy = -2; dy <= 2; ++dy) {
        #pragma unroll
        for (int dx = -2; dx <= 2; ++dx) {
            const float k = SK[dy + 2][dx + 2];
            if (k != 0.f) {
                const int yy = hy + dy, xx = wx + dx;
                if (yy >= 0 && yy < H && xx >= 0 && xx < W)
                    sc = fmaf(k, food[yy * W + xx], sc);
            }
        }
    }
    return sc;
}

// Phase A: stencil -> perceive -> MLP (scent terms pre-folded into BE) -> nx, pre-alive
#define PHASE_A(IDX, BE, NX0, NX1, NX2, PRE) do {                                   \
    const float4 a00 = st[(IDX)-SW-1], a01 = st[(IDX)-SW], a02 = st[(IDX)-SW+1];    \
    const float4 a10 = st[(IDX)-1],    a11 = st[(IDX)],    a12 = st[(IDX)+1];       \
    const float4 a20 = st[(IDX)+SW-1], a21 = st[(IDX)+SW], a22 = st[(IDX)+SW+1];    \
    const float y0 = a11.x, y1 = a11.y, y2 = a11.z;                                 \
    const float y3 = ((a02.x-a00.x) + 2.f*(a12.x-a10.x) + (a22.x-a20.x))*0.125f;    \
    const float y4 = ((a02.y-a00.y) + 2.f*(a12.y-a10.y) + (a22.y-a20.y))*0.125f;    \
    const float y5 = ((a02.z-a00.z) + 2.f*(a12.z-a10.z) + (a22.z-a20.z))*0.125f;    \
    const float y6 = ((a20.x+2.f*a21.x+a22.x) - (a00.x+2.f*a01.x+a02.x))*0.125f;    \
    const float y7 = ((a20.y+2.f*a21.y+a22.y) - (a00.y+2.f*a01.y+a02.y))*0.125f;    \
    const float y8 = ((a20.z+2.f*a21.z+a22.z) - (a00.z+2.f*a01.z+a02.z))*0.125f;    \
    const float mx = fmaxf(fmaxf(fmaxf(a00.x,a01.x), fmaxf(a02.x,a10.x)),           \
                     fmaxf(fmaxf(a11.x,a12.x), fmaxf(fmaxf(a20.x,a21.x),a22.x)));   \
    PRE = mx > 0.1f;                                                                \
    float d0 = b40, d1 = b41, d2 = b42;                                             \
    _Pragma("unroll")                                                               \
    for (int o = 0; o < 16; ++o) {                                                  \
        float a = BE[o];                                                            \
        a = fmaf(wp[o][0], y0, a); a = fmaf(wp[o][1], y1, a);                       \
        a = fmaf(wp[o][2], y2, a); a = fmaf(wp[o][3], y3, a);                       \
        a = fmaf(wp[o][4], y4, a); a = fmaf(wp[o][5], y5, a);                       \
        a = fmaf(wp[o][6], y6, a); a = fmaf(wp[o][7], y7, a);                       \
        a = fmaf(wp[o][8], y8, a);                                                  \
        a = fmaxf(a, 0.f);                                                          \
        d0 = fmaf(w4r0[o], a, d0); d1 = fmaf(w4r1[o], a, d1);                       \
        d2 = fmaf(w4r2[o], a, d2);                                                  \
    }                                                                               \
    NX0 = y0 + d0; NX1 = y1 + d1; NX2 = y2 + d2;                                    \
} while (0)

// Phase B: post-alive maxpool on xb -> mask -> clip -> state writeback (b128)
#define PHASE_B(IDX, NX0, NX1, NX2, PRE, SC) do {                                   \
    const float p00 = xb[(IDX)-SW-1], p01 = xb[(IDX)-SW], p02 = xb[(IDX)-SW+1];     \
    const float p10 = xb[(IDX)-1],    p11 = xb[(IDX)],    p12 = xb[(IDX)+1];        \
    const float p20 = xb[(IDX)+SW-1], p21 = xb[(IDX)+SW], p22 = xb[(IDX)+SW+1];     \
    const float mx2 = fmaxf(fmaxf(fmaxf(p00,p01), fmaxf(p02,p10)),                  \
                      fmaxf(fmaxf(p11,p12), fmaxf(fmaxf(p20,p21),p22)));            \
    const float m = ((PRE) && (mx2 > 0.1f)) ? 1.f : 0.f;                            \
    st[IDX] = make_float4(clip10((NX0)*m), clip10((NX1)*m), clip10((NX2)*m), SC);   \
} while (0)

__launch_bounds__(NT, 1)
__global__ void ca_kernel(const float* __restrict__ cell_in,
                          const float* __restrict__ food,
                          const float* __restrict__ w3,
                          const float* __restrict__ b3,
                          const float* __restrict__ w4,
                          const float* __restrict__ b4,
                          const int* __restrict__ steps_p,
                          float* __restrict__ out)
{
    __shared__ float4 st[SH * SW];   // {c0, c1, c2, scent}
    __shared__ float  xb[SH * SW];   // x[0] exchange for post-alive maxpool
    __shared__ float  red[NT];

    const int tid = (int)threadIdx.x;
    const int steps = steps_p[0];

    // zero LDS (halos must be 0: equivalent to -inf pad since threshold 0.1 > 0)
    for (int i = tid; i < SH * SW; i += NT) {
        st[i] = make_float4(0.f, 0.f, 0.f, 0.f);
        xb[i] = 0.f;
    }
    __syncthreads();

    // cell 1: tid; cell 2 (tail): 256+tid for tid<33 (wave 0 only)
    const int hy1 = tid / W, wx1 = tid % W;
    const int idx1 = (hy1 + 1) * SW + wx1 + 1;
    const bool has2 = tid < TAIL;
    const int cell2 = NT + tid;
    const int hy2 = has2 ? cell2 / W : hy1;
    const int wx2 = has2 ? cell2 % W : wx1;
    const int idx2 = (hy2 + 1) * SW + wx2 + 1;

    const float sc1 = scent_at(hy1, wx1, food);
    st[idx1] = make_float4(cell_in[tid], cell_in[NC + tid], cell_in[2 * NC + tid], sc1);
    float sc2 = 0.f;
    if (has2) {
        sc2 = scent_at(hy2, wx2, food);
        st[idx2] = make_float4(cell_in[cell2], cell_in[NC + cell2], cell_in[2 * NC + cell2], sc2);
    }
    __syncthreads();

    // ---- weights -> registers (once; fully static indexing => VGPR-resident) ----
    float wp[16][9], w4r0[16], w4r1[16], w4r2[16];
    #pragma unroll
    for (int o = 0; o < 16; ++o) {
        wp[o][0] = w3[o*12 + 0]; wp[o][1] = w3[o*12 + 1]; wp[o][2] = w3[o*12 + 2];
        wp[o][3] = w3[o*12 + 4]; wp[o][4] = w3[o*12 + 5]; wp[o][5] = w3[o*12 + 6];
        wp[o][6] = w3[o*12 + 8]; wp[o][7] = w3[o*12 + 9]; wp[o][8] = w3[o*12 + 10];
        w4r0[o] = w4[o]; w4r1[o] = w4[16 + o]; w4r2[o] = w4[32 + o];
    }
    const float b40 = b4[0], b41 = b4[1], b42 = b4[2];

    // ---- fold loop-invariant scent perception into per-cell bias be[] ----
    float be1[16], be2[16];
    {
        const float s00 = st[idx1-SW-1].w, s01 = st[idx1-SW].w, s02 = st[idx1-SW+1].w;
        const float s10 = st[idx1-1].w,    s11 = st[idx1].w,    s12 = st[idx1+1].w;
        const float s20 = st[idx1+SW-1].w, s21 = st[idx1+SW].w, s22 = st[idx1+SW+1].w;
        const float dxs = ((s02-s00) + 2.f*(s12-s10) + (s22-s20)) * 0.125f;
        const float dys = ((s20+2.f*s21+s22) - (s00+2.f*s01+s02)) * 0.125f;
        #pragma unroll
        for (int o = 0; o < 16; ++o)
            be1[o] = fmaf(w3[o*12+3], s11, fmaf(w3[o*12+7], dxs,
                     fmaf(w3[o*12+11], dys, b3[o])));
    }
    {
        const float s00 = st[idx2-SW-1].w, s01 = st[idx2-SW].w, s02 = st[idx2-SW+1].w;
        const float s11 = st[idx2].w,      s10 = st[idx2-1].w,  s12 = st[idx2+1].w;
        const float s20 = st[idx2+SW-1].w, s21 = st[idx2+SW].w, s22 = st[idx2+SW+1].w;
        const float dxs = ((s02-s00) + 2.f*(s12-s10) + (s22-s20)) * 0.125f;
        const float dys = ((s20+2.f*s21+s22) - (s00+2.f*s01+s02)) * 0.125f;
        #pragma unroll
        for (int o = 0; o < 16; ++o)
            be2[o] = fmaf(w3[o*12+3], s11, fmaf(w3[o*12+7], dxs,
                     fmaf(w3[o*12+11], dys, b3[o])));
    }

    // ---- main loop: 2 barriers/step, straight-line VALU otherwise ----
    for (int s = 0; s < steps; ++s) {
        float nA0, nA1, nA2; bool preA;
        PHASE_A(idx1, be1, nA0, nA1, nA2, preA);
        xb[idx1] = nA0;
        float nB0 = 0.f, nB1 = 0.f, nB2 = 0.f; bool preB = false;
        if (has2) {                           // wave 0 only; waves 1-3 branch over
            PHASE_A(idx2, be2, nB0, nB1, nB2, preB);
            xb[idx2] = nB0;
        }
        __syncthreads();
        PHASE_B(idx1, nA0, nA1, nA2, preA, sc1);
        if (has2) {
            PHASE_B(idx2, nB0, nB1, nB2, preB, sc2);
        }
        __syncthreads();
    }

    // ---- outputs: cell (4*289) | food (289) | living_count (1) ----
    {
        const float4 v = st[idx1];
        out[tid]          = v.x;
        out[NC + tid]     = v.y;
        out[2 * NC + tid] = v.z;
        out[3 * NC + tid] = clip10(v.w);
        out[4 * NC + tid] = food[tid];
        float acc = v.x;
        if (has2) {
            const float4 u = st[idx2];
            out[cell2]          = u.x;
            out[NC + cell2]     = u.y;
            out[2 * NC + cell2] = u.z;
            out[3 * NC + cell2] = clip10(u.w);
            out[4 * NC + cell2] = food[cell2];
            acc += u.x;
        }
        red[tid] = acc;
    }
    __syncthreads();
    if (tid < 64) {
        float s2 = red[tid] + red[tid + 64] + red[tid + 128] + red[tid + 192];
        #pragma unroll
        for (int off = 32; off > 0; off >>= 1)
            s2 += __shfl_down(s2, off, 64);
        if (tid == 0) out[5 * NC] = s2;
    }
}

}  // namespace

extern "C" void kernel_launch(void* const* d_in, const int* in_sizes, int n_in,
                              void* d_out, int out_size, void* d_ws, size_t ws_size,
                              hipStream_t stream) {
    const float* cell = (const float*)d_in[0];
    const float* food = (const float*)d_in[1];
    const float* w3   = (const float*)d_in[2];
    const float* b3   = (const float*)d_in[3];
    const float* w4   = (const float*)d_in[4];
    const float* b4   = (const float*)d_in[5];
    const int*   st   = (const int*)d_in[6];
    float* out = (float*)d_out;
    ca_kernel<<<1, NT, 0, stream>>>(cell, food, w3, b3, w4, b4, st, out);
}

// Round 3
// 414.357 us; speedup vs baseline: 1.6795x; 1.6795x over previous
//
#include <hip/hip_runtime.h>

namespace {

constexpr int H = 17, W = 17, NC = H * W;   // 289 cells
constexpr int SW = 20, SH = 19;             // LDS tile with 1-wide zero halo
constexpr int NT = 256;                     // 4 waves, 1 wave/SIMD, 512-VGPR budget
constexpr int TAIL = NC - NT;               // 33 tail cells handled by wave 0

// Pin a float into a VGPR: the empty asm "redefines" the value, so the
// compiler can neither rematerialize the originating global load inside the
// step loop nor fold it away. (Guide rule #17 idiom, used in reverse.)
#define PIN(x) asm volatile("" : "+v"(x))

__device__ __forceinline__ float clip10(float v) {
    return fminf(fmaxf(v, -10.f), 10.f);
}

__device__ __forceinline__ float scent_at(int hy, int wx, const float* __restrict__ food) {
    const float SK[5][5] = {
        {0.f,   .125f, .25f, .125f, 0.f},
        {.125f, .25f,  .5f,  .25f,  .125f},
        {.25f,  .5f,   1.f,  .5f,   .25f},
        {.125f, .25f,  .5f,  .25f,  .125f},
        {0.f,   .125f, .25f, .125f, 0.f}};
    float sc = 0.f;
    #pragma unroll
    for (int dy = -2; dy <= 2; ++dy) {
        #pragma unroll
        for (int dx = -2; dx <= 2; ++dx) {
            const float k = SK[dy + 2][dx + 2];
            if (k != 0.f) {
                const int yy = hy + dy, xx = wx + dx;
                if (yy >= 0 && yy < H && xx >= 0 && xx < W)
                    sc = fmaf(k, food[yy * W + xx], sc);
            }
        }
    }
    return sc;
}

// Phase A: stencil -> perceive -> MLP (scent terms pre-folded into BE) -> nx, pre-alive
#define PHASE_A(IDX, BE, NX0, NX1, NX2, PRE) do {                                   \
    const float4 a00 = st[(IDX)-SW-1], a01 = st[(IDX)-SW], a02 = st[(IDX)-SW+1];    \
    const float4 a10 = st[(IDX)-1],    a11 = st[(IDX)],    a12 = st[(IDX)+1];       \
    const float4 a20 = st[(IDX)+SW-1], a21 = st[(IDX)+SW], a22 = st[(IDX)+SW+1];    \
    const float y0 = a11.x, y1 = a11.y, y2 = a11.z;                                 \
    const float y3 = ((a02.x-a00.x) + 2.f*(a12.x-a10.x) + (a22.x-a20.x))*0.125f;    \
    const float y4 = ((a02.y-a00.y) + 2.f*(a12.y-a10.y) + (a22.y-a20.y))*0.125f;    \
    const float y5 = ((a02.z-a00.z) + 2.f*(a12.z-a10.z) + (a22.z-a20.z))*0.125f;    \
    const float y6 = ((a20.x+2.f*a21.x+a22.x) - (a00.x+2.f*a01.x+a02.x))*0.125f;    \
    const float y7 = ((a20.y+2.f*a21.y+a22.y) - (a00.y+2.f*a01.y+a02.y))*0.125f;    \
    const float y8 = ((a20.z+2.f*a21.z+a22.z) - (a00.z+2.f*a01.z+a02.z))*0.125f;    \
    const float mx = fmaxf(fmaxf(fmaxf(a00.x,a01.x), fmaxf(a02.x,a10.x)),           \
                     fmaxf(fmaxf(a11.x,a12.x), fmaxf(fmaxf(a20.x,a21.x),a22.x)));   \
    PRE = mx > 0.1f;                                                                \
    float d0 = b40, d1 = b41, d2 = b42;                                             \
    _Pragma("unroll")                                                               \
    for (int o = 0; o < 16; ++o) {                                                  \
        float a = BE[o];                                                            \
        a = fmaf(wp[o][0], y0, a); a = fmaf(wp[o][1], y1, a);                       \
        a = fmaf(wp[o][2], y2, a); a = fmaf(wp[o][3], y3, a);                       \
        a = fmaf(wp[o][4], y4, a); a = fmaf(wp[o][5], y5, a);                       \
        a = fmaf(wp[o][6], y6, a); a = fmaf(wp[o][7], y7, a);                       \
        a = fmaf(wp[o][8], y8, a);                                                  \
        a = fmaxf(a, 0.f);                                                          \
        d0 = fmaf(w4r0[o], a, d0); d1 = fmaf(w4r1[o], a, d1);                       \
        d2 = fmaf(w4r2[o], a, d2);                                                  \
    }                                                                               \
    NX0 = y0 + d0; NX1 = y1 + d1; NX2 = y2 + d2;                                    \
} while (0)

// Phase B: post-alive maxpool on xb -> mask -> clip -> state writeback (b128)
#define PHASE_B(IDX, NX0, NX1, NX2, PRE, SC) do {                                   \
    const float p00 = xb[(IDX)-SW-1], p01 = xb[(IDX)-SW], p02 = xb[(IDX)-SW+1];     \
    const float p10 = xb[(IDX)-1],    p11 = xb[(IDX)],    p12 = xb[(IDX)+1];        \
    const float p20 = xb[(IDX)+SW-1], p21 = xb[(IDX)+SW], p22 = xb[(IDX)+SW+1];     \
    const float mx2 = fmaxf(fmaxf(fmaxf(p00,p01), fmaxf(p02,p10)),                  \
                      fmaxf(fmaxf(p11,p12), fmaxf(fmaxf(p20,p21),p22)));            \
    const float m = ((PRE) && (mx2 > 0.1f)) ? 1.f : 0.f;                            \
    st[IDX] = make_float4(clip10((NX0)*m), clip10((NX1)*m), clip10((NX2)*m), SC);   \
} while (0)

__launch_bounds__(NT, 1)
__global__ void ca_kernel(const float* __restrict__ cell_in,
                          const float* __restrict__ food,
                          const float* __restrict__ w3,
                          const float* __restrict__ b3,
                          const float* __restrict__ w4,
                          const float* __restrict__ b4,
                          const int* __restrict__ steps_p,
                          float* __restrict__ out)
{
    __shared__ float4 st[SH * SW];   // {c0, c1, c2, scent}
    __shared__ float  xb[SH * SW];   // x[0] exchange for post-alive maxpool
    __shared__ float  red[NT];

    const int tid = (int)threadIdx.x;
    const int steps = steps_p[0];

    // zero LDS (halos must be 0: equivalent to -inf pad since threshold 0.1 > 0)
    for (int i = tid; i < SH * SW; i += NT) {
        st[i] = make_float4(0.f, 0.f, 0.f, 0.f);
        xb[i] = 0.f;
    }
    __syncthreads();

    // cell 1: tid; cell 2 (tail): 256+tid for tid<33 (wave 0 only)
    const int hy1 = tid / W, wx1 = tid % W;
    const int idx1 = (hy1 + 1) * SW + wx1 + 1;
    const bool has2 = tid < TAIL;
    const int cell2 = NT + tid;
    const int hy2 = has2 ? cell2 / W : hy1;
    const int wx2 = has2 ? cell2 % W : wx1;
    const int idx2 = (hy2 + 1) * SW + wx2 + 1;

    const float sc1 = scent_at(hy1, wx1, food);
    st[idx1] = make_float4(cell_in[tid], cell_in[NC + tid], cell_in[2 * NC + tid], sc1);
    float sc2 = 0.f;
    if (has2) {
        sc2 = scent_at(hy2, wx2, food);
        st[idx2] = make_float4(cell_in[cell2], cell_in[NC + cell2], cell_in[2 * NC + cell2], sc2);
    }
    __syncthreads();

    // ---- weights -> registers, once ----
    float wp[16][9], w4r0[16], w4r1[16], w4r2[16];
    #pragma unroll
    for (int o = 0; o < 16; ++o) {
        wp[o][0] = w3[o*12 + 0]; wp[o][1] = w3[o*12 + 1]; wp[o][2] = w3[o*12 + 2];
        wp[o][3] = w3[o*12 + 4]; wp[o][4] = w3[o*12 + 5]; wp[o][5] = w3[o*12 + 6];
        wp[o][6] = w3[o*12 + 8]; wp[o][7] = w3[o*12 + 9]; wp[o][8] = w3[o*12 + 10];
        w4r0[o] = w4[o]; w4r1[o] = w4[16 + o]; w4r2[o] = w4[32 + o];
    }
    float b40 = b4[0], b41 = b4[1], b42 = b4[2];

    // ---- fold loop-invariant scent perception into per-cell bias be[] ----
    float be1[16], be2[16];
    {
        const float s00 = st[idx1-SW-1].w, s01 = st[idx1-SW].w, s02 = st[idx1-SW+1].w;
        const float s10 = st[idx1-1].w,    s11 = st[idx1].w,    s12 = st[idx1+1].w;
        const float s20 = st[idx1+SW-1].w, s21 = st[idx1+SW].w, s22 = st[idx1+SW+1].w;
        const float dxs = ((s02-s00) + 2.f*(s12-s10) + (s22-s20)) * 0.125f;
        const float dys = ((s20+2.f*s21+s22) - (s00+2.f*s01+s02)) * 0.125f;
        #pragma unroll
        for (int o = 0; o < 16; ++o)
            be1[o] = fmaf(w3[o*12+3], s11, fmaf(w3[o*12+7], dxs,
                     fmaf(w3[o*12+11], dys, b3[o])));
    }
    {
        const float s00 = st[idx2-SW-1].w, s01 = st[idx2-SW].w, s02 = st[idx2-SW+1].w;
        const float s11 = st[idx2].w,      s10 = st[idx2-1].w,  s12 = st[idx2+1].w;
        const float s20 = st[idx2+SW-1].w, s21 = st[idx2+SW].w, s22 = st[idx2+SW+1].w;
        const float dxs = ((s02-s00) + 2.f*(s12-s10) + (s22-s20)) * 0.125f;
        const float dys = ((s20+2.f*s21+s22) - (s00+2.f*s01+s02)) * 0.125f;
        #pragma unroll
        for (int o = 0; o < 16; ++o)
            be2[o] = fmaf(w3[o*12+3], s11, fmaf(w3[o*12+7], dxs,
                     fmaf(w3[o*12+11], dys, b3[o])));
    }

    // ---- pin every loop-invariant scalar into a VGPR (prevents per-step
    //      rematerialization of the weight loads; 227 floats ≈ 227 VGPRs,
    //      well under the 512/wave budget at 1 wave/SIMD) ----
    #pragma unroll
    for (int o = 0; o < 16; ++o) {
        #pragma unroll
        for (int c = 0; c < 9; ++c) PIN(wp[o][c]);
        PIN(w4r0[o]); PIN(w4r1[o]); PIN(w4r2[o]);
        PIN(be1[o]);  PIN(be2[o]);
    }
    PIN(b40); PIN(b41); PIN(b42);

    // ---- main loop: 2 barriers/step, straight-line VALU otherwise ----
    for (int s = 0; s < steps; ++s) {
        float nA0, nA1, nA2; bool preA;
        PHASE_A(idx1, be1, nA0, nA1, nA2, preA);
        xb[idx1] = nA0;
        float nB0 = 0.f, nB1 = 0.f, nB2 = 0.f; bool preB = false;
        if (has2) {                           // wave 0 only; waves 1-3 branch over
            PHASE_A(idx2, be2, nB0, nB1, nB2, preB);
            xb[idx2] = nB0;
        }
        __syncthreads();
        PHASE_B(idx1, nA0, nA1, nA2, preA, sc1);
        if (has2) {
            PHASE_B(idx2, nB0, nB1, nB2, preB, sc2);
        }
        __syncthreads();
    }

    // ---- outputs: cell (4*289) | food (289) | living_count (1) ----
    {
        const float4 v = st[idx1];
        out[tid]          = v.x;
        out[NC + tid]     = v.y;
        out[2 * NC + tid] = v.z;
        out[3 * NC + tid] = clip10(v.w);
        out[4 * NC + tid] = food[tid];
        float acc = v.x;
        if (has2) {
            const float4 u = st[idx2];
            out[cell2]          = u.x;
            out[NC + cell2]     = u.y;
            out[2 * NC + cell2] = u.z;
            out[3 * NC + cell2] = clip10(u.w);
            out[4 * NC + cell2] = food[cell2];
            acc += u.x;
        }
        red[tid] = acc;
    }
    __syncthreads();
    if (tid < 64) {
        float s2 = red[tid] + red[tid + 64] + red[tid + 128] + red[tid + 192];
        #pragma unroll
        for (int off = 32; off > 0; off >>= 1)
            s2 += __shfl_down(s2, off, 64);
        if (tid == 0) out[5 * NC] = s2;
    }
}

}  // namespace

extern "C" void kernel_launch(void* const* d_in, const int* in_sizes, int n_in,
                              void* d_out, int out_size, void* d_ws, size_t ws_size,
                              hipStream_t stream) {
    const float* cell = (const float*)d_in[0];
    const float* food = (const float*)d_in[1];
    const float* w3   = (const float*)d_in[2];
    const float* b3   = (const float*)d_in[3];
    const float* w4   = (const float*)d_in[4];
    const float* b4   = (const float*)d_in[5];
    const int*   st   = (const int*)d_in[6];
    float* out = (float*)d_out;
    ca_kernel<<<1, NT, 0, stream>>>(cell, food, w3, b3, w4, b4, st, out);
}

// Round 4
// 382.695 us; speedup vs baseline: 1.8185x; 1.0827x over previous
//
#include <hip/hip_runtime.h>

namespace {

constexpr int H = 17, W = 17, NC = H * W;   // 289 cells
constexpr int SW = 20, SH = 19;             // LDS tile stride (floats) with 1-wide zero halo
constexpr int NT = 256;                     // 4 waves, 1 wave/SIMD, full 512-VGPR budget
constexpr int TAIL = NC - NT;               // 33 tail cells handled by wave 0

// Pin a float into a VGPR at this program point (non-rematerializable afterwards).
#define PIN(x) asm volatile("" : "+v"(x))

__device__ __forceinline__ float clip10(float v) {
    return fminf(fmaxf(v, -10.f), 10.f);
}

__device__ __forceinline__ float max3f(float a, float b, float c) {
    return fmaxf(fmaxf(a, b), c);   // fuses to v_max3_f32
}

__device__ __forceinline__ float scent_at(int hy, int wx, const float* __restrict__ food) {
    const float SK[5][5] = {
        {0.f,   .125f, .25f, .125f, 0.f},
        {.125f, .25f,  .5f,  .25f,  .125f},
        {.25f,  .5f,   1.f,  .5f,   .25f},
        {.125f, .25f,  .5f,  .25f,  .125f},
        {0.f,   .125f, .25f, .125f, 0.f}};
    float sc = 0.f;
    #pragma unroll
    for (int dy = -2; dy <= 2; ++dy) {
        #pragma unroll
        for (int dx = -2; dx <= 2; ++dx) {
            const float k = SK[dy + 2][dx + 2];
            if (k != 0.f) {
                const int yy = hy + dy, xx = wx + dx;
                if (yy >= 0 && yy < H && xx >= 0 && xx < W)
                    sc = fmaf(k, food[yy * W + xx], sc);
            }
        }
    }
    return sc;
}

// 9 taps from a padded SoA float array (conflict-free b32 reads)
#define LOAD9(ARR, IDX, T)                                                        \
    const float T##00 = ARR[(IDX)-SW-1], T##01 = ARR[(IDX)-SW], T##02 = ARR[(IDX)-SW+1], \
                T##10 = ARR[(IDX)-1],    T##11 = ARR[(IDX)],    T##12 = ARR[(IDX)+1],    \
                T##20 = ARR[(IDX)+SW-1], T##21 = ARR[(IDX)+SW], T##22 = ARR[(IDX)+SW+1];

// Phase A: stencil -> perceive -> MLP (scent folded into BE; sobel scale folded
// into wp columns 3..8) -> nx, pre-alive
#define PHASE_A(IDX, BE, NX0, NX1, NX2, PRE) do {                                 \
    LOAD9(c0s, IDX, p) LOAD9(c1s, IDX, q) LOAD9(c2s, IDX, r)                      \
    const float y0 = p11, y1 = q11, y2 = r11;                                     \
    const float y3 = (p02-p00) + 2.f*(p12-p10) + (p22-p20);                       \
    const float y4 = (q02-q00) + 2.f*(q12-q10) + (q22-q20);                       \
    const float y5 = (r02-r00) + 2.f*(r12-r10) + (r22-r20);                       \
    const float y6 = (p20+2.f*p21+p22) - (p00+2.f*p01+p02);                       \
    const float y7 = (q20+2.f*q21+q22) - (q00+2.f*q01+q02);                       \
    const float y8 = (r20+2.f*r21+r22) - (r00+2.f*r01+r02);                       \
    PRE = max3f(max3f(p00,p01,p02), max3f(p10,p11,p12), max3f(p20,p21,p22)) > 0.1f; \
    float d0 = b40, d1 = b41, d2 = b42;                                           \
    _Pragma("unroll")                                                             \
    for (int o = 0; o < 16; ++o) {                                                \
        float a = BE[o];                                                          \
        a = fmaf(wp[o][0], y0, a); a = fmaf(wp[o][1], y1, a);                     \
        a = fmaf(wp[o][2], y2, a); a = fmaf(wp[o][3], y3, a);                     \
        a = fmaf(wp[o][4], y4, a); a = fmaf(wp[o][5], y5, a);                     \
        a = fmaf(wp[o][6], y6, a); a = fmaf(wp[o][7], y7, a);                     \
        a = fmaf(wp[o][8], y8, a);                                                \
        a = fmaxf(a, 0.f);                                                        \
        d0 = fmaf(w4r0[o], a, d0); d1 = fmaf(w4r1[o], a, d1);                     \
        d2 = fmaf(w4r2[o], a, d2);                                                \
    }                                                                             \
    NX0 = y0 + d0; NX1 = y1 + d1; NX2 = y2 + d2;                                  \
} while (0)

// Phase B: post-alive maxpool on xb -> mask -> clip -> SoA state writeback
#define PHASE_B(IDX, NX0, NX1, NX2, PRE) do {                                     \
    LOAD9(xb, IDX, x)                                                             \
    const float mx2 = max3f(max3f(x00,x01,x02), max3f(x10,x11,x12),               \
                            max3f(x20,x21,x22));                                  \
    const float m = ((PRE) && (mx2 > 0.1f)) ? 1.f : 0.f;                          \
    c0s[IDX] = clip10((NX0)*m);                                                   \
    c1s[IDX] = clip10((NX1)*m);                                                   \
    c2s[IDX] = clip10((NX2)*m);                                                   \
} while (0)

__global__ void
__attribute__((amdgpu_flat_work_group_size(NT, NT), amdgpu_waves_per_eu(1, 1)))
ca_kernel(const float* __restrict__ cell_in,
          const float* __restrict__ food,
          const float* __restrict__ w3,
          const float* __restrict__ b3,
          const float* __restrict__ w4,
          const float* __restrict__ b4,
          const int* __restrict__ steps_p,
          float* __restrict__ out)
{
    __shared__ float c0s[SH * SW];
    __shared__ float c1s[SH * SW];
    __shared__ float c2s[SH * SW];
    __shared__ float scs[SH * SW];   // scent (loop-invariant; only read at init/epilogue)
    __shared__ float xb[SH * SW];    // x[0] exchange for post-alive maxpool
    __shared__ float red[NT];

    const int tid = (int)threadIdx.x;
    const int steps = steps_p[0];

    // zero LDS (halos must be 0: equivalent to -inf pad since threshold 0.1 > 0)
    for (int i = tid; i < SH * SW; i += NT) {
        c0s[i] = 0.f; c1s[i] = 0.f; c2s[i] = 0.f; scs[i] = 0.f; xb[i] = 0.f;
    }
    __syncthreads();

    // cell 1: tid; cell 2 (tail): 256+tid for tid<33 (wave 0 only)
    const int hy1 = tid / W, wx1 = tid % W;
    const int idx1 = (hy1 + 1) * SW + wx1 + 1;
    const bool has2 = tid < TAIL;
    const int cell2 = NT + tid;
    const int hy2 = has2 ? cell2 / W : hy1;
    const int wx2 = has2 ? cell2 % W : wx1;
    const int idx2 = (hy2 + 1) * SW + wx2 + 1;

    c0s[idx1] = cell_in[tid];
    c1s[idx1] = cell_in[NC + tid];
    c2s[idx1] = cell_in[2 * NC + tid];
    scs[idx1] = scent_at(hy1, wx1, food);
    if (has2) {
        c0s[idx2] = cell_in[cell2];
        c1s[idx2] = cell_in[NC + cell2];
        c2s[idx2] = cell_in[2 * NC + cell2];
        scs[idx2] = scent_at(hy2, wx2, food);
    }
    __syncthreads();

    // ---- weights -> registers, once. Sobel scale 0.125 folded into cols 3..8. ----
    float wp[16][9], w4r0[16], w4r1[16], w4r2[16];
    #pragma unroll
    for (int o = 0; o < 16; ++o) {
        wp[o][0] = w3[o*12 + 0];
        wp[o][1] = w3[o*12 + 1];
        wp[o][2] = w3[o*12 + 2];
        wp[o][3] = w3[o*12 + 4] * 0.125f;
        wp[o][4] = w3[o*12 + 5] * 0.125f;
        wp[o][5] = w3[o*12 + 6] * 0.125f;
        wp[o][6] = w3[o*12 + 8] * 0.125f;
        wp[o][7] = w3[o*12 + 9] * 0.125f;
        wp[o][8] = w3[o*12 + 10] * 0.125f;
        w4r0[o] = w4[o]; w4r1[o] = w4[16 + o]; w4r2[o] = w4[32 + o];
    }
    float b40 = b4[0], b41 = b4[1], b42 = b4[2];

    // ---- fold loop-invariant scent perception into per-cell bias be[] ----
    float be1[16], be2[16];
    {
        LOAD9(scs, idx1, s)
        const float dxs = ((s02-s00) + 2.f*(s12-s10) + (s22-s20)) * 0.125f;
        const float dys = ((s20+2.f*s21+s22) - (s00+2.f*s01+s02)) * 0.125f;
        #pragma unroll
        for (int o = 0; o < 16; ++o)
            be1[o] = fmaf(w3[o*12+3], s11, fmaf(w3[o*12+7], dxs,
                     fmaf(w3[o*12+11], dys, b3[o])));
    }
    {
        LOAD9(scs, idx2, s)
        const float dxs = ((s02-s00) + 2.f*(s12-s10) + (s22-s20)) * 0.125f;
        const float dys = ((s20+2.f*s21+s22) - (s00+2.f*s01+s02)) * 0.125f;
        #pragma unroll
        for (int o = 0; o < 16; ++o)
            be2[o] = fmaf(w3[o*12+3], s11, fmaf(w3[o*12+7], dxs,
                     fmaf(w3[o*12+11], dys, b3[o])));
    }

    // ---- pin loop-invariants into VGPRs (≈230 floats; waves_per_eu(1,1)
    //      gives the allocator the full 512-VGPR file, so no spill) ----
    #pragma unroll
    for (int o = 0; o < 16; ++o) {
        #pragma unroll
        for (int c = 0; c < 9; ++c) PIN(wp[o][c]);
        PIN(w4r0[o]); PIN(w4r1[o]); PIN(w4r2[o]);
        PIN(be1[o]);  PIN(be2[o]);
    }
    PIN(b40); PIN(b41); PIN(b42);

    // ---- main loop: 2 barriers/step ----
    for (int s = 0; s < steps; ++s) {
        float nA0, nA1, nA2; bool preA;
        float nB0 = 0.f, nB1 = 0.f, nB2 = 0.f; bool preB = false;
        PHASE_A(idx1, be1, nA0, nA1, nA2, preA);
        if (has2) {                           // wave 0 only; waves 1-3 branch over
            PHASE_A(idx2, be2, nB0, nB1, nB2, preB);
        }
        xb[idx1] = nA0;
        if (has2) xb[idx2] = nB0;
        __syncthreads();
        PHASE_B(idx1, nA0, nA1, nA2, preA);
        if (has2) {
            PHASE_B(idx2, nB0, nB1, nB2, preB);
        }
        __syncthreads();
    }

    // ---- outputs: cell (4*289) | food (289) | living_count (1) ----
    {
        const float v0 = c0s[idx1];
        out[tid]          = v0;
        out[NC + tid]     = c1s[idx1];
        out[2 * NC + tid] = c2s[idx1];
        out[3 * NC + tid] = clip10(scs[idx1]);
        out[4 * NC + tid] = food[tid];
        float acc = v0;
        if (has2) {
            const float u0 = c0s[idx2];
            out[cell2]          = u0;
            out[NC + cell2]     = c1s[idx2];
            out[2 * NC + cell2] = c2s[idx2];
            out[3 * NC + cell2] = clip10(scs[idx2]);
            out[4 * NC + cell2] = food[cell2];
            acc += u0;
        }
        red[tid] = acc;
    }
    __syncthreads();
    if (tid < 64) {
        float s2 = red[tid] + red[tid + 64] + red[tid + 128] + red[tid + 192];
        #pragma unroll
        for (int off = 32; off > 0; off >>= 1)
            s2 += __shfl_down(s2, off, 64);
        if (tid == 0) out[5 * NC] = s2;
    }
}

}  // namespace

extern "C" void kernel_launch(void* const* d_in, const int* in_sizes, int n_in,
                              void* d_out, int out_size, void* d_ws, size_t ws_size,
                              hipStream_t stream) {
    const float* cell = (const float*)d_in[0];
    const float* food = (const float*)d_in[1];
    const float* w3   = (const float*)d_in[2];
    const float* b3   = (const float*)d_in[3];
    const float* w4   = (const float*)d_in[4];
    const float* b4   = (const float*)d_in[5];
    const int*   st   = (const int*)d_in[6];
    float* out = (float*)d_out;
    ca_kernel<<<1, NT, 0, stream>>>(cell, food, w3, b3, w4, b4, st, out);
}

// Round 5
// 287.445 us; speedup vs baseline: 2.4211x; 1.3314x over previous
//
#include <hip/hip_runtime.h>

namespace {

constexpr int H = 17, W = 17, NC = H * W;   // 289 cells
constexpr int SW = 20, SH = 19;             // LDS tile stride (floats), 1-wide zero halo
constexpr int NT = 320;                     // 5 waves; critical SIMD has 2 waves (TLP)

// Pin a float into a VGPR at this program point.
#define PIN(x) asm volatile("" : "+v"(x))

__device__ __forceinline__ float clip10(float v) {
    return fminf(fmaxf(v, -10.f), 10.f);
}

__device__ __forceinline__ float max3f(float a, float b, float c) {
    return fmaxf(fmaxf(a, b), c);   // fuses to v_max3_f32
}

__device__ __forceinline__ float scent_at(int hy, int wx, const float* __restrict__ food) {
    const float SK[5][5] = {
        {0.f,   .125f, .25f, .125f, 0.f},
        {.125f, .25f,  .5f,  .25f,  .125f},
        {.25f,  .5f,   1.f,  .5f,   .25f},
        {.125f, .25f,  .5f,  .25f,  .125f},
        {0.f,   .125f, .25f, .125f, 0.f}};
    float sc = 0.f;
    #pragma unroll
    for (int dy = -2; dy <= 2; ++dy) {
        #pragma unroll
        for (int dx = -2; dx <= 2; ++dx) {
            const float k = SK[dy + 2][dx + 2];
            if (k != 0.f) {
                const int yy = hy + dy, xx = wx + dx;
                if (yy >= 0 && yy < H && xx >= 0 && xx < W)
                    sc = fmaf(k, food[yy * W + xx], sc);
            }
        }
    }
    return sc;
}

// 9 taps from a padded SoA float array
#define LOAD9(ARR, IDX, T)                                                        \
    const float T##00 = ARR[(IDX)-SW-1], T##01 = ARR[(IDX)-SW], T##02 = ARR[(IDX)-SW+1], \
                T##10 = ARR[(IDX)-1],    T##11 = ARR[(IDX)],    T##12 = ARR[(IDX)+1],    \
                T##20 = ARR[(IDX)+SW-1], T##21 = ARR[(IDX)+SW], T##22 = ARR[(IDX)+SW+1];

__launch_bounds__(NT, 2)   // min 2 waves/EU -> 256-VGPR cap; live set ~210 fits
__global__ void ca_kernel(const float* __restrict__ cell_in,
                          const float* __restrict__ food,
                          const float* __restrict__ w3,
                          const float* __restrict__ b3,
                          const float* __restrict__ w4,
                          const float* __restrict__ b4,
                          const int* __restrict__ steps_p,
                          float* __restrict__ out)
{
    __shared__ float c0s[SH * SW];
    __shared__ float c1s[SH * SW];
    __shared__ float c2s[SH * SW];
    __shared__ float scs[SH * SW];   // scent (loop-invariant)
    __shared__ float xb[SH * SW];    // x[0] exchange for post-alive maxpool
    __shared__ float red[NT];

    const int tid = (int)threadIdx.x;
    const int steps = steps_p[0];
    const bool act = tid < NC;

    // zero LDS (halo zeros are decision-equivalent to -inf pad: threshold 0.1 > 0)
    for (int i = tid; i < SH * SW; i += NT) {
        c0s[i] = 0.f; c1s[i] = 0.f; c2s[i] = 0.f; scs[i] = 0.f; xb[i] = 0.f;
    }
    __syncthreads();

    const int hy = act ? tid / W : 0;
    const int wx = act ? tid % W : 0;
    const int idx = (hy + 1) * SW + wx + 1;

    if (act) {
        c0s[idx] = cell_in[tid];
        c1s[idx] = cell_in[NC + tid];
        c2s[idx] = cell_in[2 * NC + tid];
        scs[idx] = scent_at(hy, wx, food);
    }
    __syncthreads();

    // ---- weights -> registers, once. Sobel 0.125 folded into cols 3..8. ----
    float wp[16][9];
    #pragma unroll
    for (int o = 0; o < 16; ++o) {
        wp[o][0] = w3[o*12 + 0];
        wp[o][1] = w3[o*12 + 1];
        wp[o][2] = w3[o*12 + 2];
        wp[o][3] = w3[o*12 + 4] * 0.125f;
        wp[o][4] = w3[o*12 + 5] * 0.125f;
        wp[o][5] = w3[o*12 + 6] * 0.125f;
        wp[o][6] = w3[o*12 + 8] * 0.125f;
        wp[o][7] = w3[o*12 + 9] * 0.125f;
        wp[o][8] = w3[o*12 + 10] * 0.125f;
    }
    float b40 = b4[0], b41 = b4[1], b42 = b4[2];

    // ---- fold loop-invariant scent perception into per-cell bias be[] ----
    float be[16];
    {
        LOAD9(scs, idx, s)
        const float dxs = ((s02-s00) + 2.f*(s12-s10) + (s22-s20)) * 0.125f;
        const float dys = ((s20+2.f*s21+s22) - (s00+2.f*s01+s02)) * 0.125f;
        #pragma unroll
        for (int o = 0; o < 16; ++o)
            be[o] = fmaf(w3[o*12+3], s11, fmaf(w3[o*12+7], dxs,
                    fmaf(w3[o*12+11], dys, b3[o])));
    }

    // ---- pin loop-invariants: 144 + 16 + 3 = 163 floats; fits in 256 cap ----
    #pragma unroll
    for (int o = 0; o < 16; ++o) {
        #pragma unroll
        for (int c = 0; c < 9; ++c) PIN(wp[o][c]);
        PIN(be[o]);
    }
    PIN(b40); PIN(b41); PIN(b42);

    // ---- main loop: 2 barriers/step, one cell per thread ----
    for (int s = 0; s < steps; ++s) {
        float n0 = 0.f, n1 = 0.f, n2 = 0.f;
        bool pre = false;
        if (act) {
            LOAD9(c0s, idx, p) LOAD9(c1s, idx, q) LOAD9(c2s, idx, r)
            const float y0 = p11, y1 = q11, y2 = r11;
            const float y3 = (p02-p00) + 2.f*(p12-p10) + (p22-p20);
            const float y4 = (q02-q00) + 2.f*(q12-q10) + (q22-q20);
            const float y5 = (r02-r00) + 2.f*(r12-r10) + (r22-r20);
            const float y6 = (p20+2.f*p21+p22) - (p00+2.f*p01+p02);
            const float y7 = (q20+2.f*q21+q22) - (q00+2.f*q01+q02);
            const float y8 = (r20+2.f*r21+r22) - (r00+2.f*r01+r02);
            pre = max3f(max3f(p00,p01,p02), max3f(p10,p11,p12),
                        max3f(p20,p21,p22)) > 0.1f;
            float d0 = b40, d1 = b41, d2 = b42;
            #pragma unroll
            for (int o = 0; o < 16; ++o) {
                float a = be[o];
                a = fmaf(wp[o][0], y0, a); a = fmaf(wp[o][1], y1, a);
                a = fmaf(wp[o][2], y2, a); a = fmaf(wp[o][3], y3, a);
                a = fmaf(wp[o][4], y4, a); a = fmaf(wp[o][5], y5, a);
                a = fmaf(wp[o][6], y6, a); a = fmaf(wp[o][7], y7, a);
                a = fmaf(wp[o][8], y8, a);
                a = fmaxf(a, 0.f);
                d0 = fmaf(w4[o],      a, d0);   // w4 unpinned: K$-resident scalar loads
                d1 = fmaf(w4[16 + o], a, d1);
                d2 = fmaf(w4[32 + o], a, d2);
            }
            n0 = y0 + d0; n1 = y1 + d1; n2 = y2 + d2;
            xb[idx] = n0;
        }
        __syncthreads();
        if (act) {
            // post-alive maxpool; center tap n0 from register (8 LDS taps)
            const float x00 = xb[idx-SW-1], x01 = xb[idx-SW], x02 = xb[idx-SW+1];
            const float x10 = xb[idx-1],                      x12 = xb[idx+1];
            const float x20 = xb[idx+SW-1], x21 = xb[idx+SW], x22 = xb[idx+SW+1];
            const float mx2 = max3f(max3f(x00,x01,x02), max3f(x10,n0,x12),
                                    max3f(x20,x21,x22));
            const float m = (pre && (mx2 > 0.1f)) ? 1.f : 0.f;
            c0s[idx] = clip10(n0 * m);
            c1s[idx] = clip10(n1 * m);
            c2s[idx] = clip10(n2 * m);
        }
        __syncthreads();
    }

    // ---- outputs: cell (4*289) | food (289) | living_count (1) ----
    if (act) {
        const float v0 = c0s[idx];
        out[tid]          = v0;
        out[NC + tid]     = c1s[idx];
        out[2 * NC + tid] = c2s[idx];
        out[3 * NC + tid] = clip10(scs[idx]);
        out[4 * NC + tid] = food[tid];
        red[tid] = v0;
    } else {
        red[tid] = 0.f;
    }
    __syncthreads();
    if (tid < 64) {
        float s2 = red[tid] + red[tid + 64] + red[tid + 128]
                 + red[tid + 192] + red[tid + 256];
        #pragma unroll
        for (int off = 32; off > 0; off >>= 1)
            s2 += __shfl_down(s2, off, 64);
        if (tid == 0) out[5 * NC] = s2;
    }
}

}  // namespace

extern "C" void kernel_launch(void* const* d_in, const int* in_sizes, int n_in,
                              void* d_out, int out_size, void* d_ws, size_t ws_size,
                              hipStream_t stream) {
    const float* cell = (const float*)d_in[0];
    const float* food = (const float*)d_in[1];
    const float* w3   = (const float*)d_in[2];
    const float* b3   = (const float*)d_in[3];
    const float* w4   = (const float*)d_in[4];
    const float* b4   = (const float*)d_in[5];
    const int*   st   = (const int*)d_in[6];
    float* out = (float*)d_out;
    ca_kernel<<<1, NT, 0, stream>>>(cell, food, w3, b3, w4, b4, st, out);
}